// Round 3
// baseline (366.341 us; speedup 1.0000x reference)
//
#include <hip/hip_runtime.h>
#include <math.h>

// Multi-scale region distillation loss — v3: async global->LDS staging.
// Block = 256 threads (4 waves) owns 256 contiguous pixels of one scale.
// K-loop: 32 stages of 8 channels; each stage stages 16 planes (8 ch x {f,fo})
// of 1 KB each into LDS via global_load_lds (16B/lane, one instr per plane per
// wave), double-buffered. Thread t accumulates dot/na2/nb2 for pixel t from
// LDS. Tail: cosine -> label -> shared class bins -> global atomics into
// ws[scale*64 + {0..31 sim, 32..63 cnt}].

#define EPSV 1e-8f

typedef const __attribute__((address_space(1))) void GV;
typedef __attribute__((address_space(3))) void LV;

__device__ __forceinline__ void gl_lds16(const float* gp, float* lp) {
    __builtin_amdgcn_global_load_lds((GV*)gp, (LV*)lp, 16, 0, 0);
}

__global__ __launch_bounds__(256)
void msrd_main(const float* __restrict__ f0, const float* __restrict__ fo0,
               const float* __restrict__ f1, const float* __restrict__ fo1,
               const float* __restrict__ f2, const float* __restrict__ fo2,
               const float* __restrict__ f3, const float* __restrict__ fo3,
               const int*   __restrict__ labels,
               const int*   __restrict__ p_nclass,
               float* __restrict__ ws)
{
    const int bid = blockIdx.x;
    int scale, win, logW, logHW, sshift;
    const float *f, *fo;
    // 256-px windows: [0,512) s0, [512,640) s1, [640,672) s2, [672,680) s3
    if (bid < 512)      { scale = 0; win = bid;       f = f0; fo = fo0; logW = 7; logHW = 14; sshift = 2; }
    else if (bid < 640) { scale = 1; win = bid - 512; f = f1; fo = fo1; logW = 6; logHW = 12; sshift = 3; }
    else if (bid < 672) { scale = 2; win = bid - 640; f = f2; fo = fo2; logW = 5; logHW = 10; sshift = 4; }
    else                { scale = 3; win = bid - 672; f = f3; fo = fo3; logW = 4; logHW = 8;  sshift = 5; }
    const int W = 1 << logW;

    const int tid  = threadIdx.x;
    const int wave = tid >> 6;
    const int lane = tid & 63;

    const int pxbase = win << 8;               // window base pixel (flat in scale)
    const int b      = pxbase >> logHW;        // window never crosses an image (HW >= 256)
    const int wrem   = pxbase & ((1 << logHW) - 1);

    __shared__ float lds[2][16][256];          // [buf][plane][px]  (32 KB)
    __shared__ float bin_sim[32], bin_cnt[32];
    if (tid < 32) { bin_sim[tid] = 0.f; bin_cnt[tid] = 0.f; }

    const size_t img_off = ((size_t)(b << 8)) << logHW;   // b*256*HW

    // wave w stages planes 4w..4w+3; plane p: tensor p>>3, channel-in-chunk p&7
    const int   p0    = wave * 4;
    const float* base0 = (p0 < 8) ? f : fo;    // all 4 planes of a wave share tensor? no: p0..p0+3
    (void)base0;

    float dot = 0.f, na2 = 0.f, nb2 = 0.f;

    // stage issuer: chunk rotated per block to decorrelate DRAM phase
    #define ISSUE(s, buf)                                                        \
        {                                                                        \
            const int chunk = ((s) + bid) & 31;                                  \
            _Pragma("unroll")                                                    \
            for (int k = 0; k < 4; ++k) {                                        \
                const int p  = p0 + k;                                           \
                const float* tb = (p < 8) ? f : fo;                              \
                const int ch = chunk * 8 + (p & 7);                              \
                const float* gp = tb + img_off + (((size_t)ch) << logHW)         \
                                   + wrem + lane * 4;                            \
                gl_lds16(gp, &lds[(buf)][p][0]);                                 \
            }                                                                    \
        }

    ISSUE(0, 0);
    __syncthreads();   // drain stage 0

    #pragma unroll 1
    for (int s = 0; s < 32; ++s) {
        const int buf = s & 1;
        if (s < 31) ISSUE(s + 1, buf ^ 1);
        #pragma unroll
        for (int c = 0; c < 8; ++c) {
            const float x = lds[buf][c][tid];
            const float y = lds[buf][8 + c][tid];
            dot = fmaf(x, y, dot);
            na2 = fmaf(x, x, na2);
            nb2 = fmaf(y, y, nb2);
        }
        __syncthreads();  // next buffer complete + safe to overwrite this one
    }

    // per-pixel finalize
    const float na  = fmaxf(sqrtf(na2), EPSV);
    const float nb  = fmaxf(sqrtf(nb2), EPSV);
    const float sim = dot / (na * nb);

    const int p   = wrem + tid;
    const int h   = p >> logW;
    const int col = p & (W - 1);
    const int lidx = (b << 18) + ((h << sshift) << 9) + (col << sshift);
    const int lab  = labels[lidx];
    const int nclass = *p_nclass;
    if ((unsigned)lab < (unsigned)nclass) {
        atomicAdd(&bin_sim[lab], sim);
        atomicAdd(&bin_cnt[lab], 1.0f);
    }
    __syncthreads();

    if (tid < 32) {
        float sv = bin_sim[tid], cv = bin_cnt[tid];
        if (sv != 0.f || cv != 0.f) {
            atomicAdd(&ws[scale * 64 + tid],      sv);
            atomicAdd(&ws[scale * 64 + 32 + tid], cv);
        }
    }
    #undef ISSUE
}

__global__ void msrd_final(const float* __restrict__ ws,
                           const int* __restrict__ p_nclass,
                           const int* __restrict__ p_nold,
                           float* __restrict__ out)
{
    if (threadIdx.x == 0 && blockIdx.x == 0) {
        const int nc = *p_nclass;
        const int no = *p_nold;
        const float wgt[4] = {1.f, 2.f, 3.f, 4.f};
        float loss = 0.f;
        for (int s = 0; s < 4; ++s) {
            float sl = 0.f;
            for (int c = 0; c < nc && c < 32; ++c) {
                float seg = ws[s * 64 + c];
                float cnt = ws[s * 64 + 32 + c];
                if (cnt > 0.f) {
                    float factor = (c == 0) ? (float)no / (float)nc
                                            : (c <= no ? 1.f : 0.f);
                    sl += factor * (1.f - seg / fmaxf(cnt, 1.f));
                }
            }
            loss += wgt[s] * sl;
        }
        out[0] = loss;
    }
}

extern "C" void kernel_launch(void* const* d_in, const int* in_sizes, int n_in,
                              void* d_out, int out_size, void* d_ws, size_t ws_size,
                              hipStream_t stream) {
    // setup_inputs order: pseudo_labels, f0, fo0, f1, fo1, f2, fo2, f3, fo3, num_class, num_old_class
    const int*   labels = (const int*)  d_in[0];
    const float* f0  = (const float*)d_in[1];
    const float* fo0 = (const float*)d_in[2];
    const float* f1  = (const float*)d_in[3];
    const float* fo1 = (const float*)d_in[4];
    const float* f2  = (const float*)d_in[5];
    const float* fo2 = (const float*)d_in[6];
    const float* f3  = (const float*)d_in[7];
    const float* fo3 = (const float*)d_in[8];
    const int* p_nclass = (const int*)d_in[9];
    const int* p_nold   = (const int*)d_in[10];
    float* out = (float*)d_out;
    float* ws  = (float*)d_ws;

    hipMemsetAsync(ws, 0, 4 * 64 * sizeof(float), stream);
    msrd_main<<<dim3(680), dim3(256), 0, stream>>>(f0, fo0, f1, fo1, f2, fo2, f3, fo3,
                                                   labels, p_nclass, ws);
    msrd_final<<<dim3(1), dim3(64), 0, stream>>>(ws, p_nclass, p_nold, out);
}